// Round 8
// baseline (154.171 us; speedup 1.0000x reference)
//
#include <hip/hip_runtime.h>

#define GROUPS 1920
#define CH4 152

// ---------------------------------------------------------------------------
// LDS layout for the [64 rows][24 cols] X/H/U buffers:
//   row stride = 32 floats, 16B-granular XOR swizzle so that per-lane
//   row-varying scalar reads (phase A) spread across banks.
//   float index = r*32 + (((c>>2) ^ h(r)) << 2) + (c&3),  h(r)=(r+(r>>3))&7
// ---------------------------------------------------------------------------
__device__ __forceinline__ int rh(int r) { return (r + (r >> 3)) & 7; }
__device__ __forceinline__ int swz(int r, int c) {
    return (r << 5) + ((((c >> 2) ^ rh(r)) << 2) | (c & 3));
}
__device__ __forceinline__ int swz4(int r, int c4) {   // aligned float4 slot
    return (r << 5) + ((c4 ^ rh(r)) << 2);
}

// ---------- phase A: Ut[k][p] = sum_q A[q][p] * Xt[k][q] ----------
template<int DIN, int KR>
__device__ __forceinline__ void layerA(const float* buf, float* Ut,
                                       const float* A, int tid)
{
    constexpr int NT = (DIN / KR) * 3;
    if (tid < NT) {
        const int kt = tid / 3, pt = tid - kt * 3;
        const int p0 = pt * 8;
        float acc[KR][8];
        #pragma unroll
        for (int j = 0; j < KR; ++j)
            #pragma unroll
            for (int a = 0; a < 8; ++a) acc[j][a] = 0.f;
        #pragma unroll 2
        for (int q = 0; q < 22; ++q) {
            const float4 a0 = *(const float4*)(A + q * 28 + p0);
            const float4 a1 = *(const float4*)(A + q * 28 + p0 + 4);
            float xv[KR];
            #pragma unroll
            for (int j = 0; j < KR; ++j) xv[j] = buf[swz(kt * KR + j, q)];
            #pragma unroll
            for (int j = 0; j < KR; ++j) {
                acc[j][0] = fmaf(xv[j], a0.x, acc[j][0]);
                acc[j][1] = fmaf(xv[j], a0.y, acc[j][1]);
                acc[j][2] = fmaf(xv[j], a0.z, acc[j][2]);
                acc[j][3] = fmaf(xv[j], a0.w, acc[j][3]);
                acc[j][4] = fmaf(xv[j], a1.x, acc[j][4]);
                acc[j][5] = fmaf(xv[j], a1.y, acc[j][5]);
                acc[j][6] = fmaf(xv[j], a1.z, acc[j][6]);
                acc[j][7] = fmaf(xv[j], a1.w, acc[j][7]);
            }
        }
        #pragma unroll
        for (int j = 0; j < KR; ++j) {
            const int k = kt * KR + j;
            *(float4*)(Ut + swz4(k, pt * 2)) =
                make_float4(acc[j][0], acc[j][1], acc[j][2], acc[j][3]);
            *(float4*)(Ut + swz4(k, pt * 2 + 1)) =
                make_float4(acc[j][4], acc[j][5], acc[j][6], acc[j][7]);
        }
    }
}

// ---------- phase B: buf[c][p] = relu(bias[c] + sum_k Ut[k][p] * W[k][c]) ----------
template<int DIN, int DOUT, int CR>
__device__ __forceinline__ void layerB(const float* __restrict__ W,
                                       const float* __restrict__ Bb,
                                       const float* Ut, float* buf, int tid)
{
    constexpr int NT = (DOUT / CR) * 3;
    if (tid < NT) {
        const int ct = tid / 3, pt = tid - ct * 3;
        const int c0 = ct * CR;
        float acc[CR][8];
        #pragma unroll
        for (int b = 0; b < CR; ++b) {
            const float bias = Bb[c0 + b];
            #pragma unroll
            for (int a = 0; a < 8; ++a) acc[b][a] = bias;
        }
        #pragma unroll 4
        for (int k = 0; k < DIN; ++k) {
            const float4 u0 = *(const float4*)(Ut + swz4(k, pt * 2));
            const float4 u1 = *(const float4*)(Ut + swz4(k, pt * 2 + 1));
            float wv[CR];
            if constexpr (CR == 1) {
                wv[0] = W[k * DOUT + c0];
            } else if constexpr (CR == 2) {
                const float2 w2 = *(const float2*)(W + k * DOUT + c0);
                wv[0] = w2.x; wv[1] = w2.y;
            } else {
                #pragma unroll
                for (int b = 0; b < CR; b += 4) {
                    const float4 w4 = *(const float4*)(W + k * DOUT + c0 + b);
                    wv[b] = w4.x; wv[b + 1] = w4.y; wv[b + 2] = w4.z; wv[b + 3] = w4.w;
                }
            }
            #pragma unroll
            for (int b = 0; b < CR; ++b) {
                acc[b][0] = fmaf(wv[b], u0.x, acc[b][0]);
                acc[b][1] = fmaf(wv[b], u0.y, acc[b][1]);
                acc[b][2] = fmaf(wv[b], u0.z, acc[b][2]);
                acc[b][3] = fmaf(wv[b], u0.w, acc[b][3]);
                acc[b][4] = fmaf(wv[b], u1.x, acc[b][4]);
                acc[b][5] = fmaf(wv[b], u1.y, acc[b][5]);
                acc[b][6] = fmaf(wv[b], u1.z, acc[b][6]);
                acc[b][7] = fmaf(wv[b], u1.w, acc[b][7]);
            }
        }
        #pragma unroll
        for (int b = 0; b < CR; ++b) {
            const int r = c0 + b;
            *(float4*)(buf + swz4(r, pt * 2)) =
                make_float4(fmaxf(acc[b][0], 0.f), fmaxf(acc[b][1], 0.f),
                            fmaxf(acc[b][2], 0.f), fmaxf(acc[b][3], 0.f));
            *(float4*)(buf + swz4(r, pt * 2 + 1)) =
                make_float4(fmaxf(acc[b][4], 0.f), fmaxf(acc[b][5], 0.f),
                            fmaxf(acc[b][6], 0.f), fmaxf(acc[b][7], 0.f));
        }
    }
}

// Round 8: one group per 256-thread block (4 waves). Grid supplies 7.5
// blocks/CU -> 30 waves/CU (was 15): double TLP, and the wider phase splits
// (B3 CR=1, A64 KR=1, B4 CR=2) cut the critical-path FMA/thread ~1.65x.
// __launch_bounds__(256,8) caps VGPR at 64 so 8 waves/SIMD are schedulable.
__global__ __launch_bounds__(256, 8) void gcn_kernel(
    const float* __restrict__ x, const float* __restrict__ ea,
    const float* __restrict__ W1, const float* __restrict__ b1,
    const float* __restrict__ W2, const float* __restrict__ b2,
    const float* __restrict__ W3, const float* __restrict__ b3,
    const float* __restrict__ W4, const float* __restrict__ b4,
    float* __restrict__ pT)       // [16*152][128]
{
    __shared__ __align__(16) float sA[24 * 28];       // [q][p], stride 28
    __shared__ float dv[24];
    __shared__ __align__(16) float buf[64 * 32];      // swizzled [row][24]
    __shared__ __align__(16) float Ut[64 * 32];

    const int tid = threadIdx.x;
    const int g = blockIdx.x;                         // group 0..1919
    const int b = g / 120, t = g - b * 120;

    // ---- folded pad zeroing: slots 0..3 (t==0 block) / 124..127 (t==119) ----
    if (t == 0)
        for (int j = tid; j < 152 * 4; j += 256)
            pT[(((size_t)(b * 152) + (j >> 2)) << 7) + (j & 3)] = 0.f;
    if (t == 119)
        for (int j = tid; j < 152 * 4; j += 256)
            pT[(((size_t)(b * 152) + (j >> 2)) << 7) + 124 + (j & 3)] = 0.f;

    // ---- A fill: (q,p) edge weight q->p, 1 on diag, 0 pads ----
    for (int idx = tid; idx < 24 * 28; idx += 256) {
        const int q = idx / 28, p = idx - q * 28;
        float v = 0.f;
        if (q < 22 && p < 22) {
            if (q == p) v = 1.0f;
            else {
                const int e = q * 21 + p - (p > q);
                v = ea[((size_t)g * 462 + e) * 5 + 4];
            }
        }
        sA[idx] = v;
    }
    // ---- x -> buf (swizzled): Xt[k][p] ----
    for (int idx = tid; idx < 14 * 24; idx += 256) {
        const int k = idx / 24, p = idx - k * 24;
        buf[swz(k, p)] = (p < 22) ? x[((size_t)g * 22 + p) * 14 + k] : 0.f;
    }
    __syncthreads();

    if (tid < 24) {   // dinv per dst p: column sum (self-loop incl.)
        const int p = tid;
        float s = 0.f;
        #pragma unroll
        for (int q = 0; q < 22; ++q) s += sA[q * 28 + p];
        dv[p] = (s > 0.f) ? rsqrtf(s) : 0.f;
    }
    __syncthreads();
    for (int idx = tid; idx < 24 * 28; idx += 256) {
        const int q = idx / 28, p = idx - q * 28;
        if (p < 24) sA[idx] *= dv[q] * dv[p];
    }
    __syncthreads();

    layerA<14, 1>(buf, Ut, sA, tid);           __syncthreads();  // NT=42
    layerB<14, 16, 1>(W1, b1, Ut, buf, tid);   __syncthreads();  // NT=48
    layerA<16, 1>(buf, Ut, sA, tid);           __syncthreads();  // NT=48
    layerB<16, 32, 1>(W2, b2, Ut, buf, tid);   __syncthreads();  // NT=96
    layerA<32, 1>(buf, Ut, sA, tid);           __syncthreads();  // NT=96
    layerB<32, 64, 1>(W3, b3, Ut, buf, tid);   __syncthreads();  // NT=192
    layerA<64, 1>(buf, Ut, sA, tid);           __syncthreads();  // NT=192

    // ---- layer 4 phase B fused with mean-pool (Ht never materialized) ----
    // CR=2 -> NT = 76*3 = 228 lanes active across 4 waves.
    float* pscr = sA;   // [3][152] partials; sA dead after layerA<64> + barrier
    if (tid < 76 * 3) {
        const int ct = tid / 3, pt = tid - ct * 3;
        const int c0 = ct * 2;
        float acc[2][8];
        #pragma unroll
        for (int bb = 0; bb < 2; ++bb) {
            const float bias = b4[c0 + bb];
            #pragma unroll
            for (int a = 0; a < 8; ++a) acc[bb][a] = bias;
        }
        #pragma unroll 4
        for (int k = 0; k < 64; ++k) {
            const float4 u0 = *(const float4*)(Ut + swz4(k, pt * 2));
            const float4 u1 = *(const float4*)(Ut + swz4(k, pt * 2 + 1));
            const float2 w2 = *(const float2*)(W4 + k * 152 + c0);
            const float wv[2] = {w2.x, w2.y};
            #pragma unroll
            for (int bb = 0; bb < 2; ++bb) {
                acc[bb][0] = fmaf(wv[bb], u0.x, acc[bb][0]);
                acc[bb][1] = fmaf(wv[bb], u0.y, acc[bb][1]);
                acc[bb][2] = fmaf(wv[bb], u0.z, acc[bb][2]);
                acc[bb][3] = fmaf(wv[bb], u0.w, acc[bb][3]);
                acc[bb][4] = fmaf(wv[bb], u1.x, acc[bb][4]);
                acc[bb][5] = fmaf(wv[bb], u1.y, acc[bb][5]);
                acc[bb][6] = fmaf(wv[bb], u1.z, acc[bb][6]);
                acc[bb][7] = fmaf(wv[bb], u1.w, acc[bb][7]);
            }
        }
        const int alim = (pt == 2) ? 6 : 8;   // mask pad cols 22,23
        float ps[2];
        #pragma unroll
        for (int bb = 0; bb < 2; ++bb) {
            float s = 0.f;
            #pragma unroll
            for (int a = 0; a < 8; ++a)
                s += (a < alim) ? fmaxf(acc[bb][a], 0.f) : 0.f;
            ps[bb] = s;
        }
        *(float2*)(pscr + pt * 152 + c0) = make_float2(ps[0], ps[1]);
    }
    __syncthreads();

    {   // transposed store: pT[b*152+c][4+t]
        float* basep = pT + (((size_t)(b * 152)) << 7) + 4 + t;
        for (int c = tid; c < 152; c += 256) {
            const float s = pscr[c] + pscr[152 + c] + pscr[304 + c];
            basep[(size_t)c << 7] = s * (1.0f / 22.0f);
        }
    }
}

// conv+BN+sigmoid+capsnorm (unchanged from round 7): t-per-lane coalesced f
// VMEM + w on the scalar pipe via readfirstlane-uniform wave id.
__global__ __launch_bounds__(256) void conv_caps_kernel(
    const float* __restrict__ pT, const float* __restrict__ cw,
    const float* __restrict__ cb, const float* __restrict__ gamma,
    const float* __restrict__ beta, float* __restrict__ out)
{
    __shared__ float sp[4 * 64];

    const int bx = blockIdx.x;              // 544 = 16 * 34
    const int b = bx / 34, r = bx - b * 34;
    const int n = r >> 1, thalf = r & 1;
    const int tid = threadIdx.x;
    const int wq = __builtin_amdgcn_readfirstlane(tid >> 6);   // SGPR wave id
    const int lane = tid & 63;
    const bool act = (lane < 60);
    const int t = act ? (thalf * 60 + lane) : 119;   // clamp idle lanes in-bounds

    const float sct = gamma[t] * 0.999500374688f;    // 1/sqrt(1+1e-3)
    const float sht = beta[t];

    const int o0 = wq * 68 + n;                      // (wq*4)*17 + n  — uniform
    float a0 = cb[o0], a1 = cb[o0 + 17], a2 = cb[o0 + 34], a3 = cb[o0 + 51];

    const float* pf  = pT + (((size_t)b * 152) << 7) + 3 + t;  // slot 3+t = f(i, t-1)
    const float* wp0 = cw + (size_t)o0 * 456;        // uniform scalar pointers
    const float* wp1 = wp0 + 17 * 456;
    const float* wp2 = wp0 + 34 * 456;
    const float* wp3 = wp0 + 51 * 456;

    // 38 chunks of 4 input channels: per chunk 12 consecutive w floats per
    // stream (merge to 3 x s_load_dwordx4) + 12 coalesced f loads + 48 FMA.
    for (int ib = 0; ib < 38; ++ib) {
        const int iw = ib * 12;
        float wv0[12], wv1[12], wv2[12], wv3[12];
        #pragma unroll
        for (int u = 0; u < 12; ++u) {
            wv0[u] = wp0[iw + u];
            wv1[u] = wp1[iw + u];
            wv2[u] = wp2[iw + u];
            wv3[u] = wp3[iw + u];
        }
        float fv[4][3];
        #pragma unroll
        for (int u = 0; u < 4; ++u) {
            const float* fi = pf + (((size_t)(ib * 4 + u)) << 7);
            fv[u][0] = fi[0]; fv[u][1] = fi[1]; fv[u][2] = fi[2];
        }
        #pragma unroll
        for (int u = 0; u < 4; ++u) {
            const float f0 = fv[u][0], f1 = fv[u][1], f2 = fv[u][2];
            a0 = fmaf(wv0[u * 3], f0, fmaf(wv0[u * 3 + 1], f1, fmaf(wv0[u * 3 + 2], f2, a0)));
            a1 = fmaf(wv1[u * 3], f0, fmaf(wv1[u * 3 + 1], f1, fmaf(wv1[u * 3 + 2], f2, a1)));
            a2 = fmaf(wv2[u * 3], f0, fmaf(wv2[u * 3 + 1], f1, fmaf(wv2[u * 3 + 2], f2, a2)));
            a3 = fmaf(wv3[u * 3], f0, fmaf(wv3[u * 3 + 1], f1, fmaf(wv3[u * 3 + 2], f2, a3)));
        }
    }

    float sl;
    {
        float z, s, d;
        z = fmaf(a0, sct, sht); s = 1.0f / (1.0f + __expf(-z)); d = s - 0.5f; sl  = d * d;
        z = fmaf(a1, sct, sht); s = 1.0f / (1.0f + __expf(-z)); d = s - 0.5f; sl += d * d;
        z = fmaf(a2, sct, sht); s = 1.0f / (1.0f + __expf(-z)); d = s - 0.5f; sl += d * d;
        z = fmaf(a3, sct, sht); s = 1.0f / (1.0f + __expf(-z)); d = s - 0.5f; sl += d * d;
    }
    sp[wq * 64 + lane] = sl;
    __syncthreads();

    if (wq == 0 && act) {
        const float s = sp[lane] + sp[64 + lane] + sp[128 + lane] + sp[192 + lane];
        out[((size_t)b * 120 + t) * 17 + n] = sqrtf(s) * 0.5f;
    }
}

extern "C" void kernel_launch(void* const* d_in, const int* in_sizes, int n_in,
                              void* d_out, int out_size, void* d_ws, size_t ws_size,
                              hipStream_t stream) {
    const float* x     = (const float*)d_in[0];
    // d_in[1] edge_index / d_in[2] batch are structurally known -> unused
    const float* ea    = (const float*)d_in[3];
    const float* W1    = (const float*)d_in[4];
    const float* b1    = (const float*)d_in[5];
    const float* W2    = (const float*)d_in[6];
    const float* b2    = (const float*)d_in[7];
    const float* W3    = (const float*)d_in[8];
    const float* b3    = (const float*)d_in[9];
    const float* W4    = (const float*)d_in[10];
    const float* b4    = (const float*)d_in[11];
    const float* cw    = (const float*)d_in[12];
    const float* cb    = (const float*)d_in[13];
    const float* gamma = (const float*)d_in[14];
    const float* beta  = (const float*)d_in[15];
    float* out = (float*)d_out;

    float* pT = (float*)d_ws;                    // [16*152][128] transposed pooled

    hipLaunchKernelGGL(gcn_kernel, dim3(GROUPS), dim3(256), 0, stream,
                       x, ea, W1, b1, W2, b2, W3, b3, W4, b4, pT);
    hipLaunchKernelGGL(conv_caps_kernel, dim3(16 * 34), dim3(256), 0, stream,
                       pT, cw, cb, gamma, beta, out);
}

// Round 9
// 151.003 us; speedup vs baseline: 1.0210x; 1.0210x over previous
//
#include <hip/hip_runtime.h>

#define GROUPS 1920
#define CH4 152

// ---------------------------------------------------------------------------
// LDS layout for the [64 rows][24 cols] X/H/U buffers:
//   row stride = 32 floats, 16B-granular XOR swizzle so that per-lane
//   row-varying scalar reads (phase A) spread across banks.
//   float index = r*32 + (((c>>2) ^ h(r)) << 2) + (c&3),  h(r)=(r+(r>>3))&7
// ---------------------------------------------------------------------------
__device__ __forceinline__ int rh(int r) { return (r + (r >> 3)) & 7; }
__device__ __forceinline__ int swz(int r, int c) {
    return (r << 5) + ((((c >> 2) ^ rh(r)) << 2) | (c & 3));
}
__device__ __forceinline__ int swz4(int r, int c4) {   // aligned float4 slot
    return (r << 5) + ((c4 ^ rh(r)) << 2);
}

// ---------- phase A: Ut[k][p] = sum_q A[q][p] * Xt[k][q] ----------
template<int DIN, int KR>
__device__ __forceinline__ void layerA(const float* buf, float* Ut,
                                       const float* A, int tid)
{
    constexpr int NT = (DIN / KR) * 3;
    if (tid < NT) {
        const int kt = tid / 3, pt = tid - kt * 3;
        const int p0 = pt * 8;
        float acc[KR][8];
        #pragma unroll
        for (int j = 0; j < KR; ++j)
            #pragma unroll
            for (int a = 0; a < 8; ++a) acc[j][a] = 0.f;
        #pragma unroll 2
        for (int q = 0; q < 22; ++q) {
            const float4 a0 = *(const float4*)(A + q * 28 + p0);
            const float4 a1 = *(const float4*)(A + q * 28 + p0 + 4);
            float xv[KR];
            #pragma unroll
            for (int j = 0; j < KR; ++j) xv[j] = buf[swz(kt * KR + j, q)];
            #pragma unroll
            for (int j = 0; j < KR; ++j) {
                acc[j][0] = fmaf(xv[j], a0.x, acc[j][0]);
                acc[j][1] = fmaf(xv[j], a0.y, acc[j][1]);
                acc[j][2] = fmaf(xv[j], a0.z, acc[j][2]);
                acc[j][3] = fmaf(xv[j], a0.w, acc[j][3]);
                acc[j][4] = fmaf(xv[j], a1.x, acc[j][4]);
                acc[j][5] = fmaf(xv[j], a1.y, acc[j][5]);
                acc[j][6] = fmaf(xv[j], a1.z, acc[j][6]);
                acc[j][7] = fmaf(xv[j], a1.w, acc[j][7]);
            }
        }
        #pragma unroll
        for (int j = 0; j < KR; ++j) {
            const int k = kt * KR + j;
            *(float4*)(Ut + swz4(k, pt * 2)) =
                make_float4(acc[j][0], acc[j][1], acc[j][2], acc[j][3]);
            *(float4*)(Ut + swz4(k, pt * 2 + 1)) =
                make_float4(acc[j][4], acc[j][5], acc[j][6], acc[j][7]);
        }
    }
}

// ---------- phase B: buf[c][p] = relu(bias[c] + sum_k Ut[k][p] * W[k][c]) ----------
template<int DIN, int DOUT, int CR>
__device__ __forceinline__ void layerB(const float* __restrict__ W,
                                       const float* __restrict__ Bb,
                                       const float* Ut, float* buf, int tid)
{
    constexpr int NT = (DOUT / CR) * 3;
    if (tid < NT) {
        const int ct = tid / 3, pt = tid - ct * 3;
        const int c0 = ct * CR;
        float acc[CR][8];
        #pragma unroll
        for (int b = 0; b < CR; ++b) {
            const float bias = Bb[c0 + b];
            #pragma unroll
            for (int a = 0; a < 8; ++a) acc[b][a] = bias;
        }
        #pragma unroll 4
        for (int k = 0; k < DIN; ++k) {
            const float4 u0 = *(const float4*)(Ut + swz4(k, pt * 2));
            const float4 u1 = *(const float4*)(Ut + swz4(k, pt * 2 + 1));
            float wv[CR];
            if constexpr (CR == 1) {
                wv[0] = W[k * DOUT + c0];
            } else if constexpr (CR == 2) {
                const float2 w2 = *(const float2*)(W + k * DOUT + c0);
                wv[0] = w2.x; wv[1] = w2.y;
            } else {
                #pragma unroll
                for (int b = 0; b < CR; b += 4) {
                    const float4 w4 = *(const float4*)(W + k * DOUT + c0 + b);
                    wv[b] = w4.x; wv[b + 1] = w4.y; wv[b + 2] = w4.z; wv[b + 3] = w4.w;
                }
            }
            #pragma unroll
            for (int b = 0; b < CR; ++b) {
                acc[b][0] = fmaf(wv[b], u0.x, acc[b][0]);
                acc[b][1] = fmaf(wv[b], u0.y, acc[b][1]);
                acc[b][2] = fmaf(wv[b], u0.z, acc[b][2]);
                acc[b][3] = fmaf(wv[b], u0.w, acc[b][3]);
                acc[b][4] = fmaf(wv[b], u1.x, acc[b][4]);
                acc[b][5] = fmaf(wv[b], u1.y, acc[b][5]);
                acc[b][6] = fmaf(wv[b], u1.z, acc[b][6]);
                acc[b][7] = fmaf(wv[b], u1.w, acc[b][7]);
            }
        }
        #pragma unroll
        for (int b = 0; b < CR; ++b) {
            const int r = c0 + b;
            *(float4*)(buf + swz4(r, pt * 2)) =
                make_float4(fmaxf(acc[b][0], 0.f), fmaxf(acc[b][1], 0.f),
                            fmaxf(acc[b][2], 0.f), fmaxf(acc[b][3], 0.f));
            *(float4*)(buf + swz4(r, pt * 2 + 1)) =
                make_float4(fmaxf(acc[b][4], 0.f), fmaxf(acc[b][5], 0.f),
                            fmaxf(acc[b][6], 0.f), fmaxf(acc[b][7], 0.f));
        }
    }
}

// Round 9: LDS-pipe economy. r8 showed VALUBusy invariant to occupancy (40% at
// both 15 and 30 waves/CU) -> shared LDS pipe saturated. Per phase, pick the
// largest KR/CR with NT <= 64 (one wave): total ds_read wave-instrs per block
// drop ~9.4K->~6.2K cycles. 128 thr, launch_bounds(128,4): VGPR cap 128
// (r8's (256,8) squeezed VGPR to 28 and serialized loads).
__global__ __launch_bounds__(128, 4) void gcn_kernel(
    const float* __restrict__ x, const float* __restrict__ ea,
    const float* __restrict__ W1, const float* __restrict__ b1,
    const float* __restrict__ W2, const float* __restrict__ b2,
    const float* __restrict__ W3, const float* __restrict__ b3,
    const float* __restrict__ W4, const float* __restrict__ b4,
    float* __restrict__ pT)       // [16*152][128]
{
    __shared__ __align__(16) float sA[24 * 28];       // [q][p], stride 28
    __shared__ float dv[24];
    __shared__ __align__(16) float buf[64 * 32];      // swizzled [row][24]
    __shared__ __align__(16) float Ut[64 * 32];

    const int tid = threadIdx.x;
    const int g = blockIdx.x;                         // group 0..1919
    const int b = g / 120, t = g - b * 120;

    // ---- folded pad zeroing: slots 0..3 (t==0 block) / 124..127 (t==119) ----
    if (t == 0)
        for (int j = tid; j < 152 * 4; j += 128)
            pT[(((size_t)(b * 152) + (j >> 2)) << 7) + (j & 3)] = 0.f;
    if (t == 119)
        for (int j = tid; j < 152 * 4; j += 128)
            pT[(((size_t)(b * 152) + (j >> 2)) << 7) + 124 + (j & 3)] = 0.f;

    // ---- A fill: (q,p) edge weight q->p, 1 on diag, 0 pads ----
    for (int idx = tid; idx < 24 * 28; idx += 128) {
        const int q = idx / 28, p = idx - q * 28;
        float v = 0.f;
        if (q < 22 && p < 22) {
            if (q == p) v = 1.0f;
            else {
                const int e = q * 21 + p - (p > q);
                v = ea[((size_t)g * 462 + e) * 5 + 4];
            }
        }
        sA[idx] = v;
    }
    // ---- x -> buf (swizzled): Xt[k][p] ----
    for (int idx = tid; idx < 14 * 24; idx += 128) {
        const int k = idx / 24, p = idx - k * 24;
        buf[swz(k, p)] = (p < 22) ? x[((size_t)g * 22 + p) * 14 + k] : 0.f;
    }
    __syncthreads();

    if (tid < 24) {   // dinv per dst p: column sum (self-loop incl.)
        const int p = tid;
        float s = 0.f;
        #pragma unroll
        for (int q = 0; q < 22; ++q) s += sA[q * 28 + p];
        dv[p] = (s > 0.f) ? rsqrtf(s) : 0.f;
    }
    __syncthreads();
    for (int idx = tid; idx < 24 * 28; idx += 128) {
        const int q = idx / 28, p = idx - q * 28;
        if (p < 24) sA[idx] *= dv[q] * dv[p];
    }
    __syncthreads();

    layerA<14, 1>(buf, Ut, sA, tid);           __syncthreads();  // NT=42, 1 wave
    layerB<14, 16, 1>(W1, b1, Ut, buf, tid);   __syncthreads();  // NT=48, 1 wave
    layerA<16, 1>(buf, Ut, sA, tid);           __syncthreads();  // NT=48, 1 wave
    layerB<16, 32, 2>(W2, b2, Ut, buf, tid);   __syncthreads();  // NT=48, 1 wave
    layerA<32, 2>(buf, Ut, sA, tid);           __syncthreads();  // NT=48, 1 wave
    layerB<32, 64, 4>(W3, b3, Ut, buf, tid);   __syncthreads();  // NT=48, 1 wave
    layerA<64, 4>(buf, Ut, sA, tid);           __syncthreads();  // NT=48, 1 wave

    // ---- layer 4 phase B fused with mean-pool, CR=8 -> NT=57, 1 wave ----
    float* pscr = sA;   // [3][152] partials; sA dead after layerA<64> + barrier
    if (tid < 19 * 3) {
        const int ct = tid / 3, pt = tid - ct * 3;
        const int c0 = ct * 8;
        float acc[8][8];
        #pragma unroll
        for (int bb = 0; bb < 8; ++bb) {
            const float bias = b4[c0 + bb];
            #pragma unroll
            for (int a = 0; a < 8; ++a) acc[bb][a] = bias;
        }
        #pragma unroll 2
        for (int k = 0; k < 64; ++k) {
            const float4 u0 = *(const float4*)(Ut + swz4(k, pt * 2));
            const float4 u1 = *(const float4*)(Ut + swz4(k, pt * 2 + 1));
            const float4 wa = *(const float4*)(W4 + k * 152 + c0);
            const float4 wb = *(const float4*)(W4 + k * 152 + c0 + 4);
            const float wv[8] = {wa.x, wa.y, wa.z, wa.w, wb.x, wb.y, wb.z, wb.w};
            #pragma unroll
            for (int bb = 0; bb < 8; ++bb) {
                acc[bb][0] = fmaf(wv[bb], u0.x, acc[bb][0]);
                acc[bb][1] = fmaf(wv[bb], u0.y, acc[bb][1]);
                acc[bb][2] = fmaf(wv[bb], u0.z, acc[bb][2]);
                acc[bb][3] = fmaf(wv[bb], u0.w, acc[bb][3]);
                acc[bb][4] = fmaf(wv[bb], u1.x, acc[bb][4]);
                acc[bb][5] = fmaf(wv[bb], u1.y, acc[bb][5]);
                acc[bb][6] = fmaf(wv[bb], u1.z, acc[bb][6]);
                acc[bb][7] = fmaf(wv[bb], u1.w, acc[bb][7]);
            }
        }
        const int alim = (pt == 2) ? 6 : 8;   // mask pad cols 22,23
        float ps[8];
        #pragma unroll
        for (int bb = 0; bb < 8; ++bb) {
            float s = 0.f;
            #pragma unroll
            for (int a = 0; a < 8; ++a)
                s += (a < alim) ? fmaxf(acc[bb][a], 0.f) : 0.f;
            ps[bb] = s;
        }
        *(float4*)(pscr + pt * 152 + c0)     = make_float4(ps[0], ps[1], ps[2], ps[3]);
        *(float4*)(pscr + pt * 152 + c0 + 4) = make_float4(ps[4], ps[5], ps[6], ps[7]);
    }
    __syncthreads();

    {   // transposed store: pT[b*152+c][4+t]
        float* basep = pT + (((size_t)(b * 152)) << 7) + 4 + t;
        for (int c = tid; c < 152; c += 128) {
            const float s = pscr[c] + pscr[152 + c] + pscr[304 + c];
            basep[(size_t)c << 7] = s * (1.0f / 22.0f);
        }
    }
}

// conv+BN+sigmoid+capsnorm (unchanged from round 7): t-per-lane coalesced f
// VMEM + w on the scalar pipe via readfirstlane-uniform wave id.
__global__ __launch_bounds__(256) void conv_caps_kernel(
    const float* __restrict__ pT, const float* __restrict__ cw,
    const float* __restrict__ cb, const float* __restrict__ gamma,
    const float* __restrict__ beta, float* __restrict__ out)
{
    __shared__ float sp[4 * 64];

    const int bx = blockIdx.x;              // 544 = 16 * 34
    const int b = bx / 34, r = bx - b * 34;
    const int n = r >> 1, thalf = r & 1;
    const int tid = threadIdx.x;
    const int wq = __builtin_amdgcn_readfirstlane(tid >> 6);   // SGPR wave id
    const int lane = tid & 63;
    const bool act = (lane < 60);
    const int t = act ? (thalf * 60 + lane) : 119;   // clamp idle lanes in-bounds

    const float sct = gamma[t] * 0.999500374688f;    // 1/sqrt(1+1e-3)
    const float sht = beta[t];

    const int o0 = wq * 68 + n;                      // (wq*4)*17 + n  — uniform
    float a0 = cb[o0], a1 = cb[o0 + 17], a2 = cb[o0 + 34], a3 = cb[o0 + 51];

    const float* pf  = pT + (((size_t)b * 152) << 7) + 3 + t;  // slot 3+t = f(i, t-1)
    const float* wp0 = cw + (size_t)o0 * 456;        // uniform scalar pointers
    const float* wp1 = wp0 + 17 * 456;
    const float* wp2 = wp0 + 34 * 456;
    const float* wp3 = wp0 + 51 * 456;

    // 38 chunks of 4 input channels: per chunk 12 consecutive w floats per
    // stream (merge to 3 x s_load_dwordx4) + 12 coalesced f loads + 48 FMA.
    for (int ib = 0; ib < 38; ++ib) {
        const int iw = ib * 12;
        float wv0[12], wv1[12], wv2[12], wv3[12];
        #pragma unroll
        for (int u = 0; u < 12; ++u) {
            wv0[u] = wp0[iw + u];
            wv1[u] = wp1[iw + u];
            wv2[u] = wp2[iw + u];
            wv3[u] = wp3[iw + u];
        }
        float fv[4][3];
        #pragma unroll
        for (int u = 0; u < 4; ++u) {
            const float* fi = pf + (((size_t)(ib * 4 + u)) << 7);
            fv[u][0] = fi[0]; fv[u][1] = fi[1]; fv[u][2] = fi[2];
        }
        #pragma unroll
        for (int u = 0; u < 4; ++u) {
            const float f0 = fv[u][0], f1 = fv[u][1], f2 = fv[u][2];
            a0 = fmaf(wv0[u * 3], f0, fmaf(wv0[u * 3 + 1], f1, fmaf(wv0[u * 3 + 2], f2, a0)));
            a1 = fmaf(wv1[u * 3], f0, fmaf(wv1[u * 3 + 1], f1, fmaf(wv1[u * 3 + 2], f2, a1)));
            a2 = fmaf(wv2[u * 3], f0, fmaf(wv2[u * 3 + 1], f1, fmaf(wv2[u * 3 + 2], f2, a2)));
            a3 = fmaf(wv3[u * 3], f0, fmaf(wv3[u * 3 + 1], f1, fmaf(wv3[u * 3 + 2], f2, a3)));
        }
    }

    float sl;
    {
        float z, s, d;
        z = fmaf(a0, sct, sht); s = 1.0f / (1.0f + __expf(-z)); d = s - 0.5f; sl  = d * d;
        z = fmaf(a1, sct, sht); s = 1.0f / (1.0f + __expf(-z)); d = s - 0.5f; sl += d * d;
        z = fmaf(a2, sct, sht); s = 1.0f / (1.0f + __expf(-z)); d = s - 0.5f; sl += d * d;
        z = fmaf(a3, sct, sht); s = 1.0f / (1.0f + __expf(-z)); d = s - 0.5f; sl += d * d;
    }
    sp[wq * 64 + lane] = sl;
    __syncthreads();

    if (wq == 0 && act) {
        const float s = sp[lane] + sp[64 + lane] + sp[128 + lane] + sp[192 + lane];
        out[((size_t)b * 120 + t) * 17 + n] = sqrtf(s) * 0.5f;
    }
}

extern "C" void kernel_launch(void* const* d_in, const int* in_sizes, int n_in,
                              void* d_out, int out_size, void* d_ws, size_t ws_size,
                              hipStream_t stream) {
    const float* x     = (const float*)d_in[0];
    // d_in[1] edge_index / d_in[2] batch are structurally known -> unused
    const float* ea    = (const float*)d_in[3];
    const float* W1    = (const float*)d_in[4];
    const float* b1    = (const float*)d_in[5];
    const float* W2    = (const float*)d_in[6];
    const float* b2    = (const float*)d_in[7];
    const float* W3    = (const float*)d_in[8];
    const float* b3    = (const float*)d_in[9];
    const float* W4    = (const float*)d_in[10];
    const float* b4    = (const float*)d_in[11];
    const float* cw    = (const float*)d_in[12];
    const float* cb    = (const float*)d_in[13];
    const float* gamma = (const float*)d_in[14];
    const float* beta  = (const float*)d_in[15];
    float* out = (float*)d_out;

    float* pT = (float*)d_ws;                    // [16*152][128] transposed pooled

    hipLaunchKernelGGL(gcn_kernel, dim3(GROUPS), dim3(128), 0, stream,
                       x, ea, W1, b1, W2, b2, W3, b3, W4, b4, pT);
    hipLaunchKernelGGL(conv_caps_kernel, dim3(16 * 34), dim3(256), 0, stream,
                       pT, cw, cb, gamma, beta, out);
}

// Round 11
// 147.659 us; speedup vs baseline: 1.0441x; 1.0226x over previous
//
#include <hip/hip_runtime.h>

#define GROUPS 1920

// ---------------------------------------------------------------------------
// LDS swizzle for the [64 rows][24 cols] X/H/U buffers (row stride 32 floats).
// ---------------------------------------------------------------------------
__device__ __forceinline__ int rh(int r) { return (r + (r >> 3)) & 7; }
__device__ __forceinline__ int swz(int r, int c) {
    return (r << 5) + ((((c >> 2) ^ rh(r)) << 2) | (c & 3));
}
__device__ __forceinline__ int swz4(int r, int c4) {   // aligned float4 slot
    return (r << 5) + ((c4 ^ rh(r)) << 2);
}

// ---------- phase A: Ut[k][p] = sum_q A[q][p] * Xt[k][q] ----------
template<int DIN, int KR>
__device__ __forceinline__ void layerA(const float* buf, float* Ut,
                                       const float* A, int tid)
{
    constexpr int NT = (DIN / KR) * 3;
    if (tid < NT) {
        const int kt = tid / 3, pt = tid - kt * 3;
        const int p0 = pt * 8;
        float acc[KR][8];
        #pragma unroll
        for (int j = 0; j < KR; ++j)
            #pragma unroll
            for (int a = 0; a < 8; ++a) acc[j][a] = 0.f;
        #pragma unroll 2
        for (int q = 0; q < 22; ++q) {
            const float4 a0 = *(const float4*)(A + q * 28 + p0);
            const float4 a1 = *(const float4*)(A + q * 28 + p0 + 4);
            float xv[KR];
            #pragma unroll
            for (int j = 0; j < KR; ++j) xv[j] = buf[swz(kt * KR + j, q)];
            #pragma unroll
            for (int j = 0; j < KR; ++j) {
                acc[j][0] = fmaf(xv[j], a0.x, acc[j][0]);
                acc[j][1] = fmaf(xv[j], a0.y, acc[j][1]);
                acc[j][2] = fmaf(xv[j], a0.z, acc[j][2]);
                acc[j][3] = fmaf(xv[j], a0.w, acc[j][3]);
                acc[j][4] = fmaf(xv[j], a1.x, acc[j][4]);
                acc[j][5] = fmaf(xv[j], a1.y, acc[j][5]);
                acc[j][6] = fmaf(xv[j], a1.z, acc[j][6]);
                acc[j][7] = fmaf(xv[j], a1.w, acc[j][7]);
            }
        }
        #pragma unroll
        for (int j = 0; j < KR; ++j) {
            const int k = kt * KR + j;
            *(float4*)(Ut + swz4(k, pt * 2)) =
                make_float4(acc[j][0], acc[j][1], acc[j][2], acc[j][3]);
            *(float4*)(Ut + swz4(k, pt * 2 + 1)) =
                make_float4(acc[j][4], acc[j][5], acc[j][6], acc[j][7]);
        }
    }
}

// ---------- phase B: buf[c][p] = relu(bias[c] + sum_k Ut[k][p] * W[k][c]) ----------
template<int DIN, int DOUT, int CR>
__device__ __forceinline__ void layerB(const float* __restrict__ W,
                                       const float* __restrict__ Bb,
                                       const float* Ut, float* buf, int tid)
{
    constexpr int NT = (DOUT / CR) * 3;
    if (tid < NT) {
        const int ct = tid / 3, pt = tid - ct * 3;
        const int c0 = ct * CR;
        float acc[CR][8];
        #pragma unroll
        for (int b = 0; b < CR; ++b) {
            const float bias = Bb[c0 + b];
            #pragma unroll
            for (int a = 0; a < 8; ++a) acc[b][a] = bias;
        }
        #pragma unroll 4
        for (int k = 0; k < DIN; ++k) {
            const float4 u0 = *(const float4*)(Ut + swz4(k, pt * 2));
            const float4 u1 = *(const float4*)(Ut + swz4(k, pt * 2 + 1));
            float wv[CR];
            if constexpr (CR == 1) {
                wv[0] = W[k * DOUT + c0];
            } else if constexpr (CR == 2) {
                const float2 w2 = *(const float2*)(W + k * DOUT + c0);
                wv[0] = w2.x; wv[1] = w2.y;
            } else {
                #pragma unroll
                for (int b = 0; b < CR; b += 4) {
                    const float4 w4 = *(const float4*)(W + k * DOUT + c0 + b);
                    wv[b] = w4.x; wv[b + 1] = w4.y; wv[b + 2] = w4.z; wv[b + 3] = w4.w;
                }
            }
            #pragma unroll
            for (int b = 0; b < CR; ++b) {
                acc[b][0] = fmaf(wv[b], u0.x, acc[b][0]);
                acc[b][1] = fmaf(wv[b], u0.y, acc[b][1]);
                acc[b][2] = fmaf(wv[b], u0.z, acc[b][2]);
                acc[b][3] = fmaf(wv[b], u0.w, acc[b][3]);
                acc[b][4] = fmaf(wv[b], u1.x, acc[b][4]);
                acc[b][5] = fmaf(wv[b], u1.y, acc[b][5]);
                acc[b][6] = fmaf(wv[b], u1.z, acc[b][6]);
                acc[b][7] = fmaf(wv[b], u1.w, acc[b][7]);
            }
        }
        #pragma unroll
        for (int b = 0; b < CR; ++b) {
            const int r = c0 + b;
            *(float4*)(buf + swz4(r, pt * 2)) =
                make_float4(fmaxf(acc[b][0], 0.f), fmaxf(acc[b][1], 0.f),
                            fmaxf(acc[b][2], 0.f), fmaxf(acc[b][3], 0.f));
            *(float4*)(buf + swz4(r, pt * 2 + 1)) =
                make_float4(fmaxf(acc[b][4], 0.f), fmaxf(acc[b][5], 0.f),
                            fmaxf(acc[b][6], 0.f), fmaxf(acc[b][7], 0.f));
        }
    }
}

// gcn: frozen round-9 configuration (45 us plateau of this decomposition).
__global__ __launch_bounds__(128, 4) void gcn_kernel(
    const float* __restrict__ x, const float* __restrict__ ea,
    const float* __restrict__ W1, const float* __restrict__ b1,
    const float* __restrict__ W2, const float* __restrict__ b2,
    const float* __restrict__ W3, const float* __restrict__ b3,
    const float* __restrict__ W4, const float* __restrict__ b4,
    float* __restrict__ pT)       // [16*152][128]
{
    __shared__ __align__(16) float sA[24 * 28];       // [q][p], stride 28
    __shared__ float dv[24];
    __shared__ __align__(16) float buf[64 * 32];      // swizzled [row][24]
    __shared__ __align__(16) float Ut[64 * 32];

    const int tid = threadIdx.x;
    const int g = blockIdx.x;                         // group 0..1919
    const int b = g / 120, t = g - b * 120;

    // ---- folded pad zeroing: slots 0..3 (t==0 block) / 124..127 (t==119) ----
    if (t == 0)
        for (int j = tid; j < 152 * 4; j += 128)
            pT[(((size_t)(b * 152) + (j >> 2)) << 7) + (j & 3)] = 0.f;
    if (t == 119)
        for (int j = tid; j < 152 * 4; j += 128)
            pT[(((size_t)(b * 152) + (j >> 2)) << 7) + 124 + (j & 3)] = 0.f;

    // ---- A fill: (q,p) edge weight q->p, 1 on diag, 0 pads ----
    for (int idx = tid; idx < 24 * 28; idx += 128) {
        const int q = idx / 28, p = idx - q * 28;
        float v = 0.f;
        if (q < 22 && p < 22) {
            if (q == p) v = 1.0f;
            else {
                const int e = q * 21 + p - (p > q);
                v = ea[((size_t)g * 462 + e) * 5 + 4];
            }
        }
        sA[idx] = v;
    }
    // ---- x -> buf (swizzled): Xt[k][p] ----
    for (int idx = tid; idx < 14 * 24; idx += 128) {
        const int k = idx / 24, p = idx - k * 24;
        buf[swz(k, p)] = (p < 22) ? x[((size_t)g * 22 + p) * 14 + k] : 0.f;
    }
    __syncthreads();

    if (tid < 24) {   // dinv per dst p: column sum (self-loop incl.)
        const int p = tid;
        float s = 0.f;
        #pragma unroll
        for (int q = 0; q < 22; ++q) s += sA[q * 28 + p];
        dv[p] = (s > 0.f) ? rsqrtf(s) : 0.f;
    }
    __syncthreads();
    for (int idx = tid; idx < 24 * 28; idx += 128) {
        const int q = idx / 28, p = idx - q * 28;
        if (p < 24) sA[idx] *= dv[q] * dv[p];
    }
    __syncthreads();

    layerA<14, 1>(buf, Ut, sA, tid);           __syncthreads();
    layerB<14, 16, 1>(W1, b1, Ut, buf, tid);   __syncthreads();
    layerA<16, 1>(buf, Ut, sA, tid);           __syncthreads();
    layerB<16, 32, 2>(W2, b2, Ut, buf, tid);   __syncthreads();
    layerA<32, 2>(buf, Ut, sA, tid);           __syncthreads();
    layerB<32, 64, 4>(W3, b3, Ut, buf, tid);   __syncthreads();
    layerA<64, 4>(buf, Ut, sA, tid);           __syncthreads();

    // ---- layer 4 phase B fused with mean-pool, CR=8 -> NT=57, 1 wave ----
    float* pscr = sA;   // [3][152] partials; sA dead after layerA<64> + barrier
    if (tid < 19 * 3) {
        const int ct = tid / 3, pt = tid - ct * 3;
        const int c0 = ct * 8;
        float acc[8][8];
        #pragma unroll
        for (int bb = 0; bb < 8; ++bb) {
            const float bias = b4[c0 + bb];
            #pragma unroll
            for (int a = 0; a < 8; ++a) acc[bb][a] = bias;
        }
        #pragma unroll 2
        for (int k = 0; k < 64; ++k) {
            const float4 u0 = *(const float4*)(Ut + swz4(k, pt * 2));
            const float4 u1 = *(const float4*)(Ut + swz4(k, pt * 2 + 1));
            const float4 wa = *(const float4*)(W4 + k * 152 + c0);
            const float4 wb = *(const float4*)(W4 + k * 152 + c0 + 4);
            const float wv[8] = {wa.x, wa.y, wa.z, wa.w, wb.x, wb.y, wb.z, wb.w};
            #pragma unroll
            for (int bb = 0; bb < 8; ++bb) {
                acc[bb][0] = fmaf(wv[bb], u0.x, acc[bb][0]);
                acc[bb][1] = fmaf(wv[bb], u0.y, acc[bb][1]);
                acc[bb][2] = fmaf(wv[bb], u0.z, acc[bb][2]);
                acc[bb][3] = fmaf(wv[bb], u0.w, acc[bb][3]);
                acc[bb][4] = fmaf(wv[bb], u1.x, acc[bb][4]);
                acc[bb][5] = fmaf(wv[bb], u1.y, acc[bb][5]);
                acc[bb][6] = fmaf(wv[bb], u1.z, acc[bb][6]);
                acc[bb][7] = fmaf(wv[bb], u1.w, acc[bb][7]);
            }
        }
        const int alim = (pt == 2) ? 6 : 8;   // mask pad cols 22,23
        float ps[8];
        #pragma unroll
        for (int bb = 0; bb < 8; ++bb) {
            float s = 0.f;
            #pragma unroll
            for (int a = 0; a < 8; ++a)
                s += (a < alim) ? fmaxf(acc[bb][a], 0.f) : 0.f;
            ps[bb] = s;
        }
        *(float4*)(pscr + pt * 152 + c0)     = make_float4(ps[0], ps[1], ps[2], ps[3]);
        *(float4*)(pscr + pt * 152 + c0 + 4) = make_float4(ps[4], ps[5], ps[6], ps[7]);
    }
    __syncthreads();

    {   // transposed store: pT[b*152+c][4+t]
        float* basep = pT + (((size_t)(b * 152)) << 7) + 4 + t;
        for (int c = tid; c < 152; c += 128) {
            const float s = pscr[c] + pscr[152 + c] + pscr[304 + c];
            basep[(size_t)c << 7] = s * (1.0f / 22.0f);
        }
    }
}

// conv+BN+sigmoid+capsnorm, round 11: 544 blocks x 512 thr (8 waves).
// Wave w8 = (dq = w8>>1, ih = w8&1): 4 d-accumulators over 76 input channels
// -> 4352 waves = 4.25/SIMD (was 2.1) with half the per-wave serial work.
// w uniform (scalar pipe), f lane-coalesced; 8-way partial combine in LDS,
// then one wave does sigmoid+capsnorm over all 16 d and writes out.
// Kernel boundary after gcn = the coherence fence (r10's in-kernel fusion
// hit cross-XCD L2 staleness).
__global__ __launch_bounds__(512) void conv_caps_kernel(
    const float* __restrict__ pT, const float* __restrict__ cw,
    const float* __restrict__ cb, const float* __restrict__ gamma,
    const float* __restrict__ beta, float* __restrict__ out)
{
    __shared__ float sp[8 * 4 * 64];        // [wave][acc j][lane]

    const int bx = blockIdx.x;              // 544 = 16 * 34
    const int b = bx / 34, r = bx - b * 34;
    const int n = r >> 1, thalf = r & 1;
    const int tid = threadIdx.x;
    const int w8 = __builtin_amdgcn_readfirstlane(tid >> 6);   // 0..7, SGPR
    const int dq = w8 >> 1, ih = w8 & 1;    // d-quad, i-half (both uniform)
    const int lane = tid & 63;
    const bool act = (lane < 60);
    const int tt = act ? (thalf * 60 + lane) : 119;   // clamp idle lanes

    const int o0 = dq * 68 + n;             // (dq*4)*17 + n, uniform
    float a0 = ih ? 0.f : cb[o0];
    float a1 = ih ? 0.f : cb[o0 + 17];
    float a2 = ih ? 0.f : cb[o0 + 34];
    float a3 = ih ? 0.f : cb[o0 + 51];

    const float* pf  = pT + (((size_t)(b * 152 + ih * 76)) << 7) + 3 + tt;
    const float* wp0 = cw + (size_t)o0 * 456 + ih * 228;   // uniform scalar ptrs
    const float* wp1 = wp0 + 17 * 456;
    const float* wp2 = wp0 + 34 * 456;
    const float* wp3 = wp0 + 51 * 456;

    for (int ib = 0; ib < 19; ++ib) {       // 19 chunks x 4 i = 76 channels
        const int iw = ib * 12;
        float wv0[12], wv1[12], wv2[12], wv3[12];
        #pragma unroll
        for (int v = 0; v < 12; ++v) {
            wv0[v] = wp0[iw + v];
            wv1[v] = wp1[iw + v];
            wv2[v] = wp2[iw + v];
            wv3[v] = wp3[iw + v];
        }
        float fv[4][3];
        #pragma unroll
        for (int v = 0; v < 4; ++v) {
            const float* fi = pf + (((size_t)(ib * 4 + v)) << 7);
            fv[v][0] = fi[0]; fv[v][1] = fi[1]; fv[v][2] = fi[2];
        }
        #pragma unroll
        for (int v = 0; v < 4; ++v) {
            const float f0 = fv[v][0], f1 = fv[v][1], f2 = fv[v][2];
            a0 = fmaf(wv0[v*3], f0, fmaf(wv0[v*3+1], f1, fmaf(wv0[v*3+2], f2, a0)));
            a1 = fmaf(wv1[v*3], f0, fmaf(wv1[v*3+1], f1, fmaf(wv1[v*3+2], f2, a1)));
            a2 = fmaf(wv2[v*3], f0, fmaf(wv2[v*3+1], f1, fmaf(wv2[v*3+2], f2, a2)));
            a3 = fmaf(wv3[v*3], f0, fmaf(wv3[v*3+1], f1, fmaf(wv3[v*3+2], f2, a3)));
        }
    }

    sp[(w8 * 4 + 0) * 64 + lane] = a0;
    sp[(w8 * 4 + 1) * 64 + lane] = a1;
    sp[(w8 * 4 + 2) * 64 + lane] = a2;
    sp[(w8 * 4 + 3) * 64 + lane] = a3;
    __syncthreads();

    if (tid < 64) {                         // one wave finishes all 16 d
        const int ln = tid;
        const bool a2c = (ln < 60);
        const int t2 = a2c ? (thalf * 60 + ln) : 119;
        const float sct = gamma[t2] * 0.999500374688f;   // 1/sqrt(1+1e-3)
        const float sht = beta[t2];
        float ss = 0.f;
        #pragma unroll
        for (int q2 = 0; q2 < 4; ++q2) {
            #pragma unroll
            for (int j = 0; j < 4; ++j) {
                const float v = sp[((q2 * 2 + 0) * 4 + j) * 64 + ln]
                              + sp[((q2 * 2 + 1) * 4 + j) * 64 + ln];
                const float z = fmaf(v, sct, sht);
                const float s = 1.0f / (1.0f + __expf(-z));
                const float d = s - 0.5f;
                ss += d * d;
            }
        }
        if (a2c) out[((size_t)b * 120 + t2) * 17 + n] = sqrtf(ss) * 0.5f;
    }
}

extern "C" void kernel_launch(void* const* d_in, const int* in_sizes, int n_in,
                              void* d_out, int out_size, void* d_ws, size_t ws_size,
                              hipStream_t stream) {
    const float* x     = (const float*)d_in[0];
    // d_in[1] edge_index / d_in[2] batch are structurally known -> unused
    const float* ea    = (const float*)d_in[3];
    const float* W1    = (const float*)d_in[4];
    const float* b1    = (const float*)d_in[5];
    const float* W2    = (const float*)d_in[6];
    const float* b2    = (const float*)d_in[7];
    const float* W3    = (const float*)d_in[8];
    const float* b3    = (const float*)d_in[9];
    const float* W4    = (const float*)d_in[10];
    const float* b4    = (const float*)d_in[11];
    const float* cw    = (const float*)d_in[12];
    const float* cb    = (const float*)d_in[13];
    const float* gamma = (const float*)d_in[14];
    const float* beta  = (const float*)d_in[15];
    float* out = (float*)d_out;

    float* pT = (float*)d_ws;                    // [16*152][128] transposed pooled

    hipLaunchKernelGGL(gcn_kernel, dim3(GROUPS), dim3(128), 0, stream,
                       x, ea, W1, b1, W2, b2, W3, b3, W4, b4, pT);
    hipLaunchKernelGGL(conv_caps_kernel, dim3(16 * 34), dim3(512), 0, stream,
                       pT, cw, cb, gamma, beta, out);
}